// Round 5
// baseline (195.649 us; speedup 1.0000x reference)
//
#include <hip/hip_runtime.h>

// JointBilateralFilter: B=16,C=1,H=768,W=1024 fp32, 9x9, sigma_s=2, sigma_r=0.1.
// valid = (sparse != 1.0); constant pad 1.0 => out-of-image taps never contribute
// (reflect-pad of depth is dead code). ~5% valid density.
//
// R5: R4 structure (float4-staged clamped 16x16 window per wave, ballot +
// scalar bit-scan broadcast, readfirstlane-uniformized tile constants) PLUS a
// precomputed LDS spatial table that fuses THREE things into one ds_read_b32:
//   T[dy+15][dx+15] = in-box(|dy|,|dx|<=4) ? COEF_S*(dy^2+dx^2) : -1e30
// (-1e30 => exp2 -> 0, so the 9x9 box test costs nothing). The LDS address is
// uniform-minus-lane-constant: addr = S(entry) [SALU] - (my*36+mx)*4 [VGPR],
// i.e. ONE v_sub per entry; the read issues on the LDS pipe, off the saturated
// VALU (R4 measured VALUBusy=98%). Row stride 36 => only 2-way bank aliasing
// (free). Entry body drops from ~16 VALU issues to ~9.

#define HH 768
#define WW 1024
#define BB 16

#define COEF_S (-0.18033688011112042f)   /* -log2(e)/8   */
#define COEF_R (-72.13475204444817f)     /* -50*log2(e)  */

#define TROWS 31           /* dy,dx in [-15,15] */
#define TSTRIDE 36         /* padded: 36*dmy+dmx ==0 mod 32 only for 2-way pairs */

__device__ __forceinline__ int rfl(int x) {
    return __builtin_amdgcn_readfirstlane(x);
}
__device__ __forceinline__ float rlanef(float v, int b) {
    return __int_as_float(__builtin_amdgcn_readlane(__float_as_int(v), b));
}

__global__ __launch_bounds__(256) void jbf_kernel(
    const float* __restrict__ sparse,
    const float* __restrict__ depth,
    float* __restrict__ out)
{
    __shared__ float Tab[TROWS * TSTRIDE];

    const int tid  = (int)threadIdx.x;
    const int lane = tid & 63;
    const int wv   = tid >> 6;                     // 4 independent waves / block

    // ---- one-time spatial table build (all 256 threads), then barrier
    for (int i = tid; i < TROWS * TSTRIDE; i += 256) {
        const int r = i / TSTRIDE;
        const int c = i - r * TSTRIDE;
        const float dy = (float)(r - 15);
        const float dx = (float)(c - 15);
        const bool box = (fabsf(dy) < 4.5f) & (fabsf(dx) < 4.5f);
        Tab[i] = box ? (COEF_S * fmaf(dy, dy, dx * dx)) : -1e30f;
    }
    __syncthreads();

    // wave-uniform tile constants -> force into SGPRs
    const int tx = rfl(((int)blockIdx.x << 4) + ((wv & 1) << 3));
    const int ty = rfl(((int)blockIdx.y << 4) + ((wv >> 1) << 3));
    const int px0 = rfl(min(max(tx - 4, 0), WW - 16));
    const int py0 = rfl(min(max(ty - 4, 0), HH - 16));
    // table element index of entry (ey,ex) for lane (my,mx):
    //   idx = ((ey-ty+15)*TSTRIDE + (ex-tx+15)) - (my*TSTRIDE+mx)
    // byte base for the SALU part:
    const int base0 = ((py0 - ty + 15) * TSTRIDE + (px0 - tx + 15)) << 2;

    const size_t plane = (size_t)blockIdx.z * (size_t)(HH * WW);
    const float* sp = sparse + plane;
    const float* dp = depth  + plane;

    // stage clamped 16x16 window: one float4 per lane per input
    const int ry  = lane >> 2;                     // 0..15 window row
    const int rxg = (lane & 3) << 2;               // 0,4,8,12 float4 group
    const int woff = (py0 + ry) * WW + (px0 + rxg);
    const float4 s4 = *(const float4*)(sp + woff); // px0 % 4 == 0 => aligned
    const float4 d4 = *(const float4*)(dp + woff);

    const int my = lane >> 3, mx = lane & 7;
    const int gy = ty + my,  gx = tx + mx;
    const float myd = dp[gy * WW + gx];
    const int c_lane4 = (my * TSTRIDE + mx) << 2;  // per-lane byte offset
    const char* TabB = (const char*)Tab;

    float numA = 0.0f, denA = 0.0f, numB = 0.0f, denB = 0.0f;

    #pragma unroll
    for (int k = 0; k < 4; ++k) {
        const float svk = (k == 0) ? s4.x : (k == 1) ? s4.y : (k == 2) ? s4.z : s4.w;
        const float dvk = (k == 0) ? d4.x : (k == 1) ? d4.y : (k == 2) ? d4.z : d4.w;
        const int basek = base0 + (k << 2);        // SALU
        unsigned long long m = __ballot(svk != 1.0f);
        while (m) {                                // uniform control flow
            const int b0 = (int)__builtin_ctzll(m);
            m &= (m - 1ull);
            {
                const float sv_b = rlanef(svk, b0);
                const float dv_b = rlanef(dvk, b0);
                const int se4 = basek + (b0 >> 2) * (TSTRIDE << 2)
                                      + ((b0 & 3) << 4);           // SALU
                const float t = *(const float*)(TabB + (se4 - c_lane4));
                const float diff = dv_b - myd;
                const float w = __builtin_amdgcn_exp2f(
                    fmaf(diff * COEF_R, diff, t));
                numA = fmaf(w, sv_b, numA);
                denA += w;
            }
            if (m) {                               // second, independent chain
                const int b1 = (int)__builtin_ctzll(m);
                m &= (m - 1ull);
                const float sv_b = rlanef(svk, b1);
                const float dv_b = rlanef(dvk, b1);
                const int se4 = basek + (b1 >> 2) * (TSTRIDE << 2)
                                      + ((b1 & 3) << 4);           // SALU
                const float t = *(const float*)(TabB + (se4 - c_lane4));
                const float diff = dv_b - myd;
                const float w = __builtin_amdgcn_exp2f(
                    fmaf(diff * COEF_R, diff, t));
                numB = fmaf(w, sv_b, numB);
                denB += w;
            }
        }
    }

    const float num = numA + numB;
    const float den = denA + denB;
    float res = num * __builtin_amdgcn_rcpf(den + 1e-8f);
    res = (den < 1e-8f) ? 1.0f : res;
    out[plane + (size_t)(gy * WW + gx)] = res;
}

extern "C" void kernel_launch(void* const* d_in, const int* in_sizes, int n_in,
                              void* d_out, int out_size, void* d_ws, size_t ws_size,
                              hipStream_t stream)
{
    const float* sparse = (const float*)d_in[0];
    const float* depth  = (const float*)d_in[1];
    float* out = (float*)d_out;
    dim3 grid(WW / 16, HH / 16, BB);   // 64 x 48 x 16 blocks, 4 waves each
    jbf_kernel<<<grid, dim3(256, 1, 1), 0, stream>>>(sparse, depth, out);
}